// Round 1
// baseline (268.472 us; speedup 1.0000x reference)
//
#include <hip/hip_runtime.h>
#include <math.h>
#include <stdint.h>

#define KG 64
#define KG3 (KG * KG * KG)
#define ALPHA 0.34f
#define COULOMB 138.935456f
#define CUTOFF2 81.0f
#define PI_F 3.14159265358979323846f

// ---------------------------------------------------------------- utilities

__device__ __forceinline__ void block_reduce_atomic(double v, double* red, double* acc) {
    int tid = threadIdx.x;
    red[tid] = v;
    __syncthreads();
    for (int s = blockDim.x >> 1; s > 0; s >>= 1) {
        if (tid < s) red[tid] += red[tid + s];
        __syncthreads();
    }
    if (tid == 0) atomicAdd(acc, red[0]);
}

// hdr: [0..8] inv_box (row-major), [9] |det(box)|
__global__ void setup_kernel(const float* __restrict__ box, float* __restrict__ hdr) {
    float b0 = box[0], b1 = box[1], b2 = box[2];
    float b3 = box[3], b4 = box[4], b5 = box[5];
    float b6 = box[6], b7 = box[7], b8 = box[8];
    float det = b0 * (b4 * b8 - b5 * b7) - b1 * (b3 * b8 - b5 * b6) + b2 * (b3 * b7 - b4 * b6);
    float id = 1.0f / det;
    hdr[0] = (b4 * b8 - b5 * b7) * id;
    hdr[1] = (b2 * b7 - b1 * b8) * id;
    hdr[2] = (b1 * b5 - b2 * b4) * id;
    hdr[3] = (b5 * b6 - b3 * b8) * id;
    hdr[4] = (b0 * b8 - b2 * b6) * id;
    hdr[5] = (b2 * b3 - b0 * b5) * id;
    hdr[6] = (b3 * b7 - b4 * b6) * id;
    hdr[7] = (b1 * b6 - b0 * b7) * id;
    hdr[8] = (b0 * b4 - b1 * b3) * id;
    hdr[9] = fabsf(det);
}

// ---------------------------------------------------------------- spreading

// order-4 cardinal B-spline weights, matching the reference recursion
__device__ __forceinline__ void bspline4(float t, float* w) {
    float w0 = 1.0f - t, w1 = t;
    float a2 = 0.5f * t * w1;
    float a1 = 0.5f * ((t + 1.0f) * w0 + (2.0f - t) * w1);
    float a0 = 0.5f * (1.0f - t) * w0;
    const float d = 1.0f / 3.0f;
    w[3] = d * t * a2;
    w[2] = d * ((t + 1.0f) * a1 + (3.0f - t) * a2);
    w[1] = d * ((t + 2.0f) * a0 + (2.0f - t) * a1);
    w[0] = d * (1.0f - t) * a0;
}

__global__ void spread_kernel(const float* __restrict__ pos, const float* __restrict__ chg,
                              const float* __restrict__ hdr, float* __restrict__ grid, int N) {
    int i = blockIdx.x * blockDim.x + threadIdx.x;
    if (i >= N) return;
    float inv[9];
#pragma unroll
    for (int a = 0; a < 9; a++) inv[a] = hdr[a];
    float p0 = pos[3 * i], p1 = pos[3 * i + 1], p2 = pos[3 * i + 2];
    float q = chg[i];
    float w[3][4];
    int idx[3][4];
#pragma unroll
    for (int a = 0; a < 3; a++) {
        float f = p0 * inv[0 * 3 + a] + p1 * inv[1 * 3 + a] + p2 * inv[2 * 3 + a];
        f -= floorf(f);
        float u = f * (float)KG;
        float fu = floorf(u);
        int base = (int)fu;
        float t = u - fu;
        bspline4(t, w[a]);
#pragma unroll
        for (int j = 0; j < 4; j++) idx[a][j] = (base - 3 + j + 2 * KG) & (KG - 1);
    }
#pragma unroll
    for (int jx = 0; jx < 4; jx++) {
        float qx = q * w[0][jx];
        int bx = idx[0][jx] * KG;
#pragma unroll
        for (int jy = 0; jy < 4; jy++) {
            float qxy = qx * w[1][jy];
            int bxy = (bx + idx[1][jy]) * KG;
#pragma unroll
            for (int jz = 0; jz < 4; jz++) {
                atomicAdd(&grid[bxy + idx[2][jz]], qxy * w[2][jz]);
            }
        }
    }
}

// ---------------------------------------------------------------- 3D DFT (64-pt lines)

// pass 1: real grid -> complex, DFT along z.  one block per (ix,iy) line.
__global__ void dft_z(const float* __restrict__ grid, float2* __restrict__ out) {
    __shared__ float g[KG];
    __shared__ float twc[KG], tws[KG];
    int line = blockIdx.x;  // ix*KG + iy
    int t = threadIdx.x;
    g[t] = grid[line * KG + t];
    float sv, cv;
    sincosf(-2.0f * PI_F * (float)t / (float)KG, &sv, &cv);
    twc[t] = cv;
    tws[t] = sv;
    __syncthreads();
    int m = t;
    float re = 0.0f, im = 0.0f;
#pragma unroll 8
    for (int iz = 0; iz < KG; iz++) {
        int k = (m * iz) & (KG - 1);
        float gv = g[iz];
        re += gv * twc[k];
        im += gv * tws[k];
    }
    out[line * KG + m] = make_float2(re, im);
}

// pass 2: DFT along y.  one block per (ix,mz).
__global__ void dft_y(const float2* __restrict__ in, float2* __restrict__ out) {
    __shared__ float cr[KG], ci[KG];
    __shared__ float twc[KG], tws[KG];
    int b = blockIdx.x;
    int ix = b >> 6, mz = b & 63;
    int t = threadIdx.x;
    float2 v = in[(ix * KG + t) * KG + mz];
    cr[t] = v.x;
    ci[t] = v.y;
    float sv, cv;
    sincosf(-2.0f * PI_F * (float)t / (float)KG, &sv, &cv);
    twc[t] = cv;
    tws[t] = sv;
    __syncthreads();
    int my = t;
    float re = 0.0f, im = 0.0f;
#pragma unroll 8
    for (int iy = 0; iy < KG; iy++) {
        int k = (my * iy) & (KG - 1);
        float ar = cr[iy], ai = ci[iy];
        float wr = twc[k], wi = tws[k];
        re += ar * wr - ai * wi;
        im += ar * wi + ai * wr;
    }
    out[(ix * KG + my) * KG + mz] = make_float2(re, im);
}

// pass 3 + influence reduction fused: DFT along x, then sum G(m)*|S|^2.
// one block per (my,mz); thread = mx.
__global__ void dft_x_reduce(const float2* __restrict__ in, const float* __restrict__ hdr,
                             double* __restrict__ acc) {
    __shared__ float cr[KG], ci[KG];
    __shared__ float twc[KG], tws[KG];
    __shared__ double red[KG];
    int b = blockIdx.x;
    int my = b >> 6, mz = b & 63;
    int t = threadIdx.x;
    float2 v = in[(t * KG + my) * KG + mz];
    cr[t] = v.x;
    ci[t] = v.y;
    float sv, cv;
    sincosf(-2.0f * PI_F * (float)t / (float)KG, &sv, &cv);
    twc[t] = cv;
    tws[t] = sv;
    __syncthreads();
    int mx = t;
    float re = 0.0f, im = 0.0f;
#pragma unroll 8
    for (int ix = 0; ix < KG; ix++) {
        int k = (mx * ix) & (KG - 1);
        float ar = cr[ix], ai = ci[ix];
        float wr = twc[k], wi = tws[k];
        re += ar * wr - ai * wi;
        im += ar * wi + ai * wr;
    }
    float sq = re * re + im * im;

    // |b(m)|^-2 for order 4, K=64: b(m) = 1/6 + 4/6 e^{-i th} + 1/6 e^{-2 th}
    auto bmod = [&](int m) -> float {
        int k1 = m & 63, k2 = (2 * m) & 63;
        float br = 1.0f / 6.0f + (4.0f / 6.0f) * twc[k1] + (1.0f / 6.0f) * twc[k2];
        float bi = (4.0f / 6.0f) * tws[k1] + (1.0f / 6.0f) * tws[k2];
        float d2 = br * br + bi * bi;
        return 1.0f / fmaxf(d2, 1e-7f);
    };

    int msx = (mx < KG / 2) ? mx : mx - KG;
    int msy = (my < KG / 2) ? my : my - KG;
    int msz = (mz < KG / 2) ? mz : mz - KG;
    float fmx = (float)msx, fmy = (float)msy, fmz = (float)msz;
    // kvec_a = sum_b m_b * inv_box[a][b]
    float kx = fmx * hdr[0] + fmy * hdr[1] + fmz * hdr[2];
    float ky = fmx * hdr[3] + fmy * hdr[4] + fmz * hdr[5];
    float kz = fmx * hdr[6] + fmy * hdr[7] + fmz * hdr[8];
    float msq = kx * kx + ky * ky + kz * kz;
    const float cexp = (PI_F * PI_F) / (ALPHA * ALPHA);
    float infl = (msq > 0.0f) ? expf(-cexp * msq) / msq : 0.0f;
    float vol = hdr[9];
    float pref = COULOMB / (2.0f * PI_F * vol);
    double term = (double)(pref * infl * bmod(mx) * bmod(my) * bmod(mz) * sq);

    block_reduce_atomic(term, red, acc);
}

// ---------------------------------------------------------------- direct space

#define TI 256
__global__ void direct_kernel(const float* __restrict__ pos, const float* __restrict__ chg,
                              const float* __restrict__ box, const float* __restrict__ hdr,
                              const int* __restrict__ excl, int N, int E,
                              double* __restrict__ acc) {
    int ib = blockIdx.x * TI;
    int jb = blockIdx.y * TI;
    if (jb < ib) return;  // whole tile has j <= i (tiles aligned): no upper-tri pairs

    __shared__ float sx[TI], sy[TI], sz[TI], sq[TI];
    __shared__ double red[TI];
    int tid = threadIdx.x;
    int j0 = jb + tid;
    if (j0 < N) {
        sx[tid] = pos[3 * j0];
        sy[tid] = pos[3 * j0 + 1];
        sz[tid] = pos[3 * j0 + 2];
        sq[tid] = chg[j0];
    }
    __syncthreads();

    double e = 0.0;
    int i = ib + tid;
    if (i < N) {
        float inv[9], bx[9];
#pragma unroll
        for (int a = 0; a < 9; a++) {
            inv[a] = hdr[a];
            bx[a] = box[a];
        }
        float xi = pos[3 * i], yi = pos[3 * i + 1], zi = pos[3 * i + 2];
        float qi = chg[i];
        int ex[8];
        int ne = (E < 8) ? E : 8;
        for (int k = 0; k < ne; k++) ex[k] = excl[i * E + k];

        int jmax = (N - jb < TI) ? (N - jb) : TI;
        for (int jj = 0; jj < jmax; jj++) {
            int jg = jb + jj;
            if (jg <= i) continue;
            float dx = xi - sx[jj], dy = yi - sy[jj], dz = zi - sz[jj];
            // minimum image
            float s0 = dx * inv[0] + dy * inv[3] + dz * inv[6];
            float s1 = dx * inv[1] + dy * inv[4] + dz * inv[7];
            float s2 = dx * inv[2] + dy * inv[5] + dz * inv[8];
            s0 -= rintf(s0);
            s1 -= rintf(s1);
            s2 -= rintf(s2);
            float ddx = s0 * bx[0] + s1 * bx[3] + s2 * bx[6];
            float ddy = s0 * bx[1] + s1 * bx[4] + s2 * bx[7];
            float ddz = s0 * bx[2] + s1 * bx[5] + s2 * bx[8];
            float r2 = ddx * ddx + ddy * ddy + ddz * ddz;
            if (r2 < CUTOFF2) {
                bool skip = false;
                for (int k = 0; k < ne; k++) skip = skip || (ex[k] == jg);
                if (!skip) {
                    float r = sqrtf(r2);
                    e += (double)(qi * sq[jj] * erfcf(ALPHA * r) / r);
                }
            }
        }
        e *= (double)COULOMB;
    }
    block_reduce_atomic(e, red, acc);
}

// ---------------------------------------------------------------- self + exclusion corr.

__global__ void excl_self_kernel(const float* __restrict__ pos, const float* __restrict__ chg,
                                 const float* __restrict__ box, const float* __restrict__ hdr,
                                 const int* __restrict__ excl, int N, int E,
                                 double* __restrict__ acc) {
    __shared__ double red[256];
    int i = blockIdx.x * blockDim.x + threadIdx.x;
    double e = 0.0;
    if (i < N) {
        const float inv_sqrt_pi = 0.5641895835477563f;
        float qi = chg[i];
        e += (double)(-COULOMB * ALPHA * inv_sqrt_pi * qi * qi);  // self energy

        float inv[9], bx[9];
#pragma unroll
        for (int a = 0; a < 9; a++) {
            inv[a] = hdr[a];
            bx[a] = box[a];
        }
        float xi = pos[3 * i], yi = pos[3 * i + 1], zi = pos[3 * i + 2];
        for (int k = 0; k < E; k++) {
            int j = excl[i * E + k];
            if (j < 0) continue;
            float dx = xi - pos[3 * j], dy = yi - pos[3 * j + 1], dz = zi - pos[3 * j + 2];
            float s0 = dx * inv[0] + dy * inv[3] + dz * inv[6];
            float s1 = dx * inv[1] + dy * inv[4] + dz * inv[7];
            float s2 = dx * inv[2] + dy * inv[5] + dz * inv[8];
            s0 -= rintf(s0);
            s1 -= rintf(s1);
            s2 -= rintf(s2);
            float ddx = s0 * bx[0] + s1 * bx[3] + s2 * bx[6];
            float ddy = s0 * bx[1] + s1 * bx[4] + s2 * bx[7];
            float ddz = s0 * bx[2] + s1 * bx[5] + s2 * bx[8];
            float r2 = ddx * ddx + ddy * ddy + ddz * ddz;
            if (r2 > 0.0f) {
                float r = sqrtf(r2);
                float qj = chg[j];
                e += (double)(-0.5f * COULOMB * qi * qj * erff(ALPHA * r) / r);
            }
        }
    }
    block_reduce_atomic(e, red, acc);
}

__global__ void finalize_kernel(const double* __restrict__ acc, float* __restrict__ out) {
    out[0] = (float)acc[0];
}

// ---------------------------------------------------------------- launch

extern "C" void kernel_launch(void* const* d_in, const int* in_sizes, int n_in,
                              void* d_out, int out_size, void* d_ws, size_t ws_size,
                              hipStream_t stream) {
    const float* pos = (const float*)d_in[0];
    const float* chg = (const float*)d_in[1];
    const float* box = (const float*)d_in[2];
    const int* excl = (const int*)d_in[3];
    int N = in_sizes[0] / 3;
    int E = in_sizes[3] / N;

    char* ws = (char*)d_ws;
    double* acc = (double*)ws;                       // 8 B
    float* hdr = (float*)(ws + 16);                  // 10 floats
    float* grid = (float*)(ws + 1024);               // KG3 floats (1 MB)
    float2* bufA = (float2*)(ws + 1024 + 4 * KG3);   // KG3 float2 (2 MB)
    float2* bufB = (float2*)(ws + 1024 + 12 * KG3);  // KG3 float2 (2 MB)

    // zero accumulator + real grid (header gets rewritten by setup_kernel)
    hipMemsetAsync(ws, 0, 1024 + 4 * (size_t)KG3, stream);

    setup_kernel<<<1, 1, 0, stream>>>(box, hdr);
    spread_kernel<<<(N + 63) / 64, 64, 0, stream>>>(pos, chg, hdr, grid, N);
    dft_z<<<KG * KG, KG, 0, stream>>>(grid, bufA);
    dft_y<<<KG * KG, KG, 0, stream>>>(bufA, bufB);
    dft_x_reduce<<<KG * KG, KG, 0, stream>>>(bufB, hdr, acc);

    int nt = (N + TI - 1) / TI;
    dim3 dg(nt, nt);
    direct_kernel<<<dg, TI, 0, stream>>>(pos, chg, box, hdr, excl, N, E, acc);
    excl_self_kernel<<<nt, 256, 0, stream>>>(pos, chg, box, hdr, excl, N, E, acc);
    finalize_kernel<<<1, 1, 0, stream>>>(acc, (float*)d_out);
}

// Round 2
// 190.767 us; speedup vs baseline: 1.4073x; 1.4073x over previous
//
#include <hip/hip_runtime.h>
#include <math.h>
#include <stdint.h>

#define KG 64
#define KG3 (KG * KG * KG)
#define ALPHA 0.34f
#define COULOMB 138.935456f
#define CUTOFF2 81.0f
#define PI_F 3.14159265358979323846f

// ---------------------------------------------------------------- setup
// hdr: [0..8] inv_box (row-major), [9] |det|, [10] diagonal-box flag
__global__ void setup_kernel(const float* __restrict__ box, float* __restrict__ hdr) {
    float b0 = box[0], b1 = box[1], b2 = box[2];
    float b3 = box[3], b4 = box[4], b5 = box[5];
    float b6 = box[6], b7 = box[7], b8 = box[8];
    float det = b0 * (b4 * b8 - b5 * b7) - b1 * (b3 * b8 - b5 * b6) + b2 * (b3 * b7 - b4 * b6);
    float id = 1.0f / det;
    hdr[0] = (b4 * b8 - b5 * b7) * id;
    hdr[1] = (b2 * b7 - b1 * b8) * id;
    hdr[2] = (b1 * b5 - b2 * b4) * id;
    hdr[3] = (b5 * b6 - b3 * b8) * id;
    hdr[4] = (b0 * b8 - b2 * b6) * id;
    hdr[5] = (b2 * b3 - b0 * b5) * id;
    hdr[6] = (b3 * b7 - b4 * b6) * id;
    hdr[7] = (b1 * b6 - b0 * b7) * id;
    hdr[8] = (b0 * b4 - b1 * b3) * id;
    hdr[9] = fabsf(det);
    bool diag = (b1 == 0.0f) && (b2 == 0.0f) && (b3 == 0.0f) && (b5 == 0.0f) &&
                (b6 == 0.0f) && (b7 == 0.0f);
    hdr[10] = diag ? 1.0f : 0.0f;
}

// ---------------------------------------------------------------- spreading
__device__ __forceinline__ void bspline4(float t, float* w) {
    float w0 = 1.0f - t, w1 = t;
    float a2 = 0.5f * t * w1;
    float a1 = 0.5f * ((t + 1.0f) * w0 + (2.0f - t) * w1);
    float a0 = 0.5f * (1.0f - t) * w0;
    const float d = 1.0f / 3.0f;
    w[3] = d * t * a2;
    w[2] = d * ((t + 1.0f) * a1 + (3.0f - t) * a2);
    w[1] = d * ((t + 2.0f) * a0 + (2.0f - t) * a1);
    w[0] = d * (1.0f - t) * a0;
}

__global__ void spread_kernel(const float* __restrict__ pos, const float* __restrict__ chg,
                              const float* __restrict__ hdr, float* __restrict__ grid,
                              float4* __restrict__ pxq, int N) {
    int i = blockIdx.x * blockDim.x + threadIdx.x;
    if (i >= N) return;
    float inv[9];
#pragma unroll
    for (int a = 0; a < 9; a++) inv[a] = hdr[a];
    float p0 = pos[3 * i], p1 = pos[3 * i + 1], p2 = pos[3 * i + 2];
    float q = chg[i];
    pxq[i] = make_float4(p0, p1, p2, q);  // packed array for direct kernel
    float w[3][4];
    int idx[3][4];
#pragma unroll
    for (int a = 0; a < 3; a++) {
        float f = p0 * inv[0 * 3 + a] + p1 * inv[1 * 3 + a] + p2 * inv[2 * 3 + a];
        f -= floorf(f);
        float u = f * (float)KG;
        float fu = floorf(u);
        int base = (int)fu;
        float t = u - fu;
        bspline4(t, w[a]);
#pragma unroll
        for (int j = 0; j < 4; j++) idx[a][j] = (base - 3 + j + 2 * KG) & (KG - 1);
    }
#pragma unroll
    for (int jx = 0; jx < 4; jx++) {
        float qx = q * w[0][jx];
        int bx = idx[0][jx] * KG;
#pragma unroll
        for (int jy = 0; jy < 4; jy++) {
            float qxy = qx * w[1][jy];
            int bxy = (bx + idx[1][jy]) * KG;
#pragma unroll
            for (int jz = 0; jz < 4; jz++) {
                atomicAdd(&grid[bxy + idx[2][jz]], qxy * w[2][jz]);
            }
        }
    }
}

// ---------------------------------------------------------------- direct space
// 64x64 atom tiles, one wave per tile, upper-triangular tiles only.
// Self-energy + exclusion corrections folded into diagonal tiles.
#define DT 64
__global__ __launch_bounds__(64) void direct_kernel(
    const float4* __restrict__ pxq, const float* __restrict__ box,
    const float* __restrict__ hdr, const int* __restrict__ excl, int N, int E,
    double* __restrict__ acc) {
    int ib = blockIdx.x * DT, jb = blockIdx.y * DT;
    if (jb < ib) return;

    __shared__ float4 sj[DT];
    int t = threadIdx.x;
    int jg0 = jb + t;
    sj[t] = (jg0 < N) ? pxq[jg0] : make_float4(1e30f, 1e30f, 1e30f, 0.0f);
    __syncthreads();

    bool diag = hdr[10] != 0.0f;
    double e = 0.0;
    int i = ib + t;
    if (i < N) {
        float4 me = pxq[i];
        float xi = me.x, yi = me.y, zi = me.z, qi = me.w;
        int ex[8];
        int ne = (E < 8) ? E : 8;
        for (int k = 0; k < ne; k++) ex[k] = excl[i * E + k];
        int jmax = (N - jb < DT) ? (N - jb) : DT;

        if (diag) {
            float Lx = box[0], Ly = box[4], Lz = box[8];
            float ivx = hdr[0], ivy = hdr[4], ivz = hdr[8];
            for (int jj = 0; jj < jmax; jj++) {
                float4 o = sj[jj];
                float dx = xi - o.x, dy = yi - o.y, dz = zi - o.z;
                dx -= rintf(dx * ivx) * Lx;
                dy -= rintf(dy * ivy) * Ly;
                dz -= rintf(dz * ivz) * Lz;
                float r2 = dx * dx + dy * dy + dz * dz;
                int jg = jb + jj;
                if (r2 < CUTOFF2 && jg > i) {
                    bool skip = false;
                    for (int k = 0; k < ne; k++) skip = skip || (ex[k] == jg);
                    if (!skip) {
                        float r = sqrtf(r2);
                        e += (double)(qi * o.w * erfcf(ALPHA * r) / r);
                    }
                }
            }
        } else {
            float inv[9], bx[9];
#pragma unroll
            for (int a = 0; a < 9; a++) {
                inv[a] = hdr[a];
                bx[a] = box[a];
            }
            for (int jj = 0; jj < jmax; jj++) {
                float4 o = sj[jj];
                float dx = xi - o.x, dy = yi - o.y, dz = zi - o.z;
                float s0 = dx * inv[0] + dy * inv[3] + dz * inv[6];
                float s1 = dx * inv[1] + dy * inv[4] + dz * inv[7];
                float s2 = dx * inv[2] + dy * inv[5] + dz * inv[8];
                s0 -= rintf(s0);
                s1 -= rintf(s1);
                s2 -= rintf(s2);
                float ddx = s0 * bx[0] + s1 * bx[3] + s2 * bx[6];
                float ddy = s0 * bx[1] + s1 * bx[4] + s2 * bx[7];
                float ddz = s0 * bx[2] + s1 * bx[5] + s2 * bx[8];
                float r2 = ddx * ddx + ddy * ddy + ddz * ddz;
                int jg = jb + jj;
                if (r2 < CUTOFF2 && jg > i) {
                    bool skip = false;
                    for (int k = 0; k < ne; k++) skip = skip || (ex[k] == jg);
                    if (!skip) {
                        float r = sqrtf(r2);
                        e += (double)(qi * o.w * erfcf(ALPHA * r) / r);
                    }
                }
            }
        }
        e *= (double)COULOMB;

        // diagonal tile: fold in self-energy + exclusion corrections for atom i
        if (ib == jb) {
            const float inv_sqrt_pi = 0.5641895835477563f;
            e += (double)(-COULOMB * ALPHA * inv_sqrt_pi * qi * qi);
            for (int k = 0; k < E; k++) {
                int j = excl[i * E + k];
                if (j < 0) continue;
                float4 o = pxq[j];
                float dx = xi - o.x, dy = yi - o.y, dz = zi - o.z;
                if (diag) {
                    dx -= rintf(dx * hdr[0]) * box[0];
                    dy -= rintf(dy * hdr[4]) * box[4];
                    dz -= rintf(dz * hdr[8]) * box[8];
                } else {
                    float s0 = dx * hdr[0] + dy * hdr[3] + dz * hdr[6];
                    float s1 = dx * hdr[1] + dy * hdr[4] + dz * hdr[7];
                    float s2 = dx * hdr[2] + dy * hdr[5] + dz * hdr[8];
                    s0 -= rintf(s0);
                    s1 -= rintf(s1);
                    s2 -= rintf(s2);
                    dx = s0 * box[0] + s1 * box[3] + s2 * box[6];
                    dy = s0 * box[1] + s1 * box[4] + s2 * box[7];
                    dz = s0 * box[2] + s1 * box[5] + s2 * box[8];
                }
                float r2 = dx * dx + dy * dy + dz * dz;
                if (r2 > 0.0f) {
                    float r = sqrtf(r2);
                    e += (double)(-0.5f * COULOMB * qi * o.w * erff(ALPHA * r) / r);
                }
            }
        }
    }
    // single-wave block: shuffle reduction, no barriers
#pragma unroll
    for (int off = 32; off > 0; off >>= 1) e += __shfl_down(e, off, 64);
    if (t == 0) atomicAdd(acc, e);
}

// ---------------------------------------------------------------- 3D DFT, 64-pt lines
// Register complex-rotation recurrence for twiddles (no LDS table, no conflicts).
// Layouts chosen so every pass READS coalesced; scattered writes absorbed by L2.

// pass 1: real grid[ix][iy][iz] -> bufA[ix][mz][iy]
__global__ __launch_bounds__(64) void dft_z(const float* __restrict__ grid,
                                            float2* __restrict__ bufA) {
    __shared__ float g[KG];
    int line = blockIdx.x;  // ix*KG + iy
    int t = threadIdx.x;
    g[t] = grid[line * KG + t];
    __syncthreads();
    float ss, sc;
    sincosf(-2.0f * PI_F * (float)t / (float)KG, &ss, &sc);
    float wc = 1.0f, ws = 0.0f, re = 0.0f, im = 0.0f;
#pragma unroll
    for (int iz = 0; iz < KG; iz++) {
        float gv = g[iz];
        re = fmaf(gv, wc, re);
        im = fmaf(gv, ws, im);
        float nwc = wc * sc - ws * ss;
        ws = wc * ss + ws * sc;
        wc = nwc;
    }
    int ix = line >> 6, iy = line & 63;
    bufA[(ix * KG + t) * KG + iy] = make_float2(re, im);
}

// pass 2: bufA[ix][mz][iy] -> bufB[my][mz][ix]
__global__ __launch_bounds__(64) void dft_y(const float2* __restrict__ bufA,
                                            float2* __restrict__ bufB) {
    __shared__ float2 c[KG];
    int b = blockIdx.x;  // ix*KG + mz
    int ix = b >> 6, mz = b & 63;
    int t = threadIdx.x;
    c[t] = bufA[(ix * KG + mz) * KG + t];
    __syncthreads();
    float ss, sc;
    sincosf(-2.0f * PI_F * (float)t / (float)KG, &ss, &sc);
    float wc = 1.0f, ws = 0.0f, re = 0.0f, im = 0.0f;
#pragma unroll
    for (int iy = 0; iy < KG; iy++) {
        float2 a = c[iy];
        re += a.x * wc - a.y * ws;
        im += a.x * ws + a.y * wc;
        float nwc = wc * sc - ws * ss;
        ws = wc * ss + ws * sc;
        wc = nwc;
    }
    bufB[(t * KG + mz) * KG + ix] = make_float2(re, im);
}

__device__ __forceinline__ float bmod4(float c1, float s1) {
    // |b(m)|^-2 for order 4: b = (1 + 4 e^{i th} + e^{2i th})/6
    float c2 = 2.0f * c1 * c1 - 1.0f;
    float s2 = 2.0f * s1 * c1;
    float br = (1.0f + 4.0f * c1 + c2) * (1.0f / 6.0f);
    float bi = (4.0f * s1 + s2) * (1.0f / 6.0f);
    float d2 = br * br + bi * bi;
    return 1.0f / fmaxf(d2, 1e-7f);
}

// pass 3 fused with influence reduction: bufB[my][mz][ix], lane = mx
__global__ __launch_bounds__(64) void dft_x_reduce(const float2* __restrict__ bufB,
                                                   const float* __restrict__ hdr,
                                                   double* __restrict__ acc) {
    __shared__ float2 c[KG];
    int b = blockIdx.x;  // my*KG + mz
    int my = b >> 6, mz = b & 63;
    int t = threadIdx.x;
    c[t] = bufB[(my * KG + mz) * KG + t];
    __syncthreads();
    float ss, sc;
    sincosf(-2.0f * PI_F * (float)t / (float)KG, &ss, &sc);
    float wc = 1.0f, ws = 0.0f, re = 0.0f, im = 0.0f;
#pragma unroll
    for (int ix = 0; ix < KG; ix++) {
        float2 a = c[ix];
        re += a.x * wc - a.y * ws;
        im += a.x * ws + a.y * wc;
        float nwc = wc * sc - ws * ss;
        ws = wc * ss + ws * sc;
        wc = nwc;
    }
    float sq = re * re + im * im;

    int mx = t;
    int msx = (mx < KG / 2) ? mx : mx - KG;
    int msy = (my < KG / 2) ? my : my - KG;
    int msz = (mz < KG / 2) ? mz : mz - KG;
    float fmx = (float)msx, fmy = (float)msy, fmz = (float)msz;
    float kx = fmx * hdr[0] + fmy * hdr[1] + fmz * hdr[2];
    float ky = fmx * hdr[3] + fmy * hdr[4] + fmz * hdr[5];
    float kz = fmx * hdr[6] + fmy * hdr[7] + fmz * hdr[8];
    float msq = kx * kx + ky * ky + kz * kz;
    const float cexp = (PI_F * PI_F) / (ALPHA * ALPHA);
    float infl = (msq > 0.0f) ? expf(-cexp * msq) / msq : 0.0f;

    // bmod factors: mx from this lane's twiddle (cos(-th)=cos(th), sign of sin squared away)
    float bx_ = bmod4(sc, ss);
    float sy, cy, sz, cz;
    sincosf(2.0f * PI_F * (float)my / (float)KG, &sy, &cy);
    sincosf(2.0f * PI_F * (float)mz / (float)KG, &sz, &cz);
    float by_ = bmod4(cy, sy);
    float bz_ = bmod4(cz, sz);

    float pref = COULOMB / (2.0f * PI_F * hdr[9]);
    double term = (double)(pref * infl * bx_ * by_ * bz_ * sq);

#pragma unroll
    for (int off = 32; off > 0; off >>= 1) term += __shfl_down(term, off, 64);
    if (t == 0) atomicAdd(acc, term);
}

__global__ void finalize_kernel(const double* __restrict__ acc, float* __restrict__ out) {
    out[0] = (float)acc[0];
}

// ---------------------------------------------------------------- launch

extern "C" void kernel_launch(void* const* d_in, const int* in_sizes, int n_in,
                              void* d_out, int out_size, void* d_ws, size_t ws_size,
                              hipStream_t stream) {
    const float* pos = (const float*)d_in[0];
    const float* chg = (const float*)d_in[1];
    const float* box = (const float*)d_in[2];
    const int* excl = (const int*)d_in[3];
    int N = in_sizes[0] / 3;
    int E = in_sizes[3] / N;

    char* ws = (char*)d_ws;
    double* acc = (double*)ws;                       // 8 B
    float* hdr = (float*)(ws + 16);                  // header floats
    float* grid = (float*)(ws + 1024);               // KG3 floats (1 MB)
    float2* bufA = (float2*)(ws + 1024 + 4 * KG3);   // KG3 float2 (2 MB)
    float2* bufB = (float2*)(ws + 1024 + 12 * KG3);  // KG3 float2 (2 MB)
    // pxq aliases the bufB region: direct_kernel (reader) runs BEFORE dft_y
    // (which overwrites bufB). Keeps ws footprint at the proven ~5.25 MB.
    float4* pxq = (float4*)(ws + 1024 + 12 * KG3);

    hipMemsetAsync(ws, 0, 1024 + 4 * (size_t)KG3, stream);  // acc + hdr + grid

    setup_kernel<<<1, 1, 0, stream>>>(box, hdr);
    spread_kernel<<<(N + 63) / 64, 64, 0, stream>>>(pos, chg, hdr, grid, pxq, N);

    int nt = (N + DT - 1) / DT;
    dim3 dg(nt, nt);
    direct_kernel<<<dg, DT, 0, stream>>>(pxq, box, hdr, excl, N, E, acc);

    dft_z<<<KG * KG, KG, 0, stream>>>(grid, bufA);
    dft_y<<<KG * KG, KG, 0, stream>>>(bufA, bufB);
    dft_x_reduce<<<KG * KG, KG, 0, stream>>>(bufB, hdr, acc);

    finalize_kernel<<<1, 1, 0, stream>>>(acc, (float*)d_out);
}

// Round 3
// 157.084 us; speedup vs baseline: 1.7091x; 1.2144x over previous
//
#include <hip/hip_runtime.h>
#include <math.h>
#include <stdint.h>

#define KG 64
#define KG3 (KG * KG * KG)
#define ALPHA 0.34f
#define COULOMB 138.935456f
#define CUTOFF2 81.0f
#define PI_F 3.14159265358979323846f

// ---------------------------------------------------------------- box helpers
// Derived per-block from the 9-float box (30 flops, cheaper than a setup launch).
struct BoxInfo {
    float inv[9];
    float vol;
    bool diag;
};
__device__ __forceinline__ BoxInfo load_box(const float* __restrict__ box) {
    BoxInfo b;
    float b0 = box[0], b1 = box[1], b2 = box[2];
    float b3 = box[3], b4 = box[4], b5 = box[5];
    float b6 = box[6], b7 = box[7], b8 = box[8];
    float det = b0 * (b4 * b8 - b5 * b7) - b1 * (b3 * b8 - b5 * b6) + b2 * (b3 * b7 - b4 * b6);
    float id = 1.0f / det;
    b.inv[0] = (b4 * b8 - b5 * b7) * id;
    b.inv[1] = (b2 * b7 - b1 * b8) * id;
    b.inv[2] = (b1 * b5 - b2 * b4) * id;
    b.inv[3] = (b5 * b6 - b3 * b8) * id;
    b.inv[4] = (b0 * b8 - b2 * b6) * id;
    b.inv[5] = (b2 * b3 - b0 * b5) * id;
    b.inv[6] = (b3 * b7 - b4 * b6) * id;
    b.inv[7] = (b1 * b6 - b0 * b7) * id;
    b.inv[8] = (b0 * b4 - b1 * b3) * id;
    b.vol = fabsf(det);
    b.diag = (b1 == 0.0f) && (b2 == 0.0f) && (b3 == 0.0f) && (b5 == 0.0f) && (b6 == 0.0f) &&
             (b7 == 0.0f);
    return b;
}

// ---------------------------------------------------------------- spreading
__device__ __forceinline__ void bspline4(float t, float* w) {
    float w0 = 1.0f - t, w1 = t;
    float a2 = 0.5f * t * w1;
    float a1 = 0.5f * ((t + 1.0f) * w0 + (2.0f - t) * w1);
    float a0 = 0.5f * (1.0f - t) * w0;
    const float d = 1.0f / 3.0f;
    w[3] = d * t * a2;
    w[2] = d * ((t + 1.0f) * a1 + (3.0f - t) * a2);
    w[1] = d * ((t + 2.0f) * a0 + (2.0f - t) * a1);
    w[0] = d * (1.0f - t) * a0;
}

__global__ __launch_bounds__(256) void spread_kernel(const float* __restrict__ pos,
                                                     const float* __restrict__ chg,
                                                     const float* __restrict__ box,
                                                     float* __restrict__ grid,
                                                     float4* __restrict__ pxq, int N) {
    int i = blockIdx.x * blockDim.x + threadIdx.x;
    if (i >= N) return;
    BoxInfo B = load_box(box);
    float p0 = pos[3 * i], p1 = pos[3 * i + 1], p2 = pos[3 * i + 2];
    float q = chg[i];
    pxq[i] = make_float4(p0, p1, p2, q);
    float w[3][4];
    int idx[3][4];
#pragma unroll
    for (int a = 0; a < 3; a++) {
        float f = p0 * B.inv[0 * 3 + a] + p1 * B.inv[1 * 3 + a] + p2 * B.inv[2 * 3 + a];
        f -= floorf(f);
        float u = f * (float)KG;
        float fu = floorf(u);
        int base = (int)fu;
        float t = u - fu;
        bspline4(t, w[a]);
#pragma unroll
        for (int j = 0; j < 4; j++) idx[a][j] = (base - 3 + j + 2 * KG) & (KG - 1);
    }
#pragma unroll
    for (int jx = 0; jx < 4; jx++) {
        float qx = q * w[0][jx];
        int bx = idx[0][jx] * KG;
#pragma unroll
        for (int jy = 0; jy < 4; jy++) {
            float qxy = qx * w[1][jy];
            int bxy = (bx + idx[1][jy]) * KG;
#pragma unroll
            for (int jz = 0; jz < 4; jz++) {
                atomicAdd(&grid[bxy + idx[2][jz]], qxy * w[2][jz]);
            }
        }
    }
}

// ---------------------------------------------------------------- direct space
// Block = 256 i-atoms vs one 64-atom j-tile. Upper-triangular tiles only.
// Partial energy per block -> partD[slot] (pre-zeroed; skipped blocks stay 0).
#define DIB 256
#define DJT 64
__global__ __launch_bounds__(256) void direct_kernel(const float4* __restrict__ pxq,
                                                     const float* __restrict__ box,
                                                     const int* __restrict__ excl, int N, int E,
                                                     double* __restrict__ partD) {
    int ib = blockIdx.x * DIB, jb = blockIdx.y * DJT;
    if (jb + DJT <= ib) return;  // fully lower-triangular

    __shared__ float4 sj[DJT];
    __shared__ double wsum[4];
    int tid = threadIdx.x;
    if (tid < DJT) {
        int jg0 = jb + tid;
        sj[tid] = (jg0 < N) ? pxq[jg0] : make_float4(1e30f, 1e30f, 1e30f, 0.0f);
    }
    __syncthreads();

    BoxInfo B = load_box(box);
    double e = 0.0;
    int i = ib + tid;
    if (i < N) {
        float4 me = pxq[i];
        float xi = me.x, yi = me.y, zi = me.z, qi = me.w;
        int ex[8];
        int ne = (E < 8) ? E : 8;
        for (int k = 0; k < ne; k++) ex[k] = excl[i * E + k];
        int jmax = (N - jb < DJT) ? (N - jb) : DJT;

        if (B.diag) {
            float Lx = box[0], Ly = box[4], Lz = box[8];
            float ivx = B.inv[0], ivy = B.inv[4], ivz = B.inv[8];
#pragma unroll 8
            for (int jj = 0; jj < jmax; jj++) {
                float4 o = sj[jj];
                float dx = xi - o.x, dy = yi - o.y, dz = zi - o.z;
                dx -= rintf(dx * ivx) * Lx;
                dy -= rintf(dy * ivy) * Ly;
                dz -= rintf(dz * ivz) * Lz;
                float r2 = dx * dx + dy * dy + dz * dz;
                int jg = jb + jj;
                if (r2 < CUTOFF2 && jg > i) {
                    bool skip = false;
                    for (int k = 0; k < ne; k++) skip = skip || (ex[k] == jg);
                    if (!skip) {
                        float r = sqrtf(r2);
                        e += (double)(qi * o.w * erfcf(ALPHA * r) / r);
                    }
                }
            }
        } else {
#pragma unroll 4
            for (int jj = 0; jj < jmax; jj++) {
                float4 o = sj[jj];
                float dx = xi - o.x, dy = yi - o.y, dz = zi - o.z;
                float s0 = dx * B.inv[0] + dy * B.inv[3] + dz * B.inv[6];
                float s1 = dx * B.inv[1] + dy * B.inv[4] + dz * B.inv[7];
                float s2 = dx * B.inv[2] + dy * B.inv[5] + dz * B.inv[8];
                s0 -= rintf(s0);
                s1 -= rintf(s1);
                s2 -= rintf(s2);
                float ddx = s0 * box[0] + s1 * box[3] + s2 * box[6];
                float ddy = s0 * box[1] + s1 * box[4] + s2 * box[7];
                float ddz = s0 * box[2] + s1 * box[5] + s2 * box[8];
                float r2 = ddx * ddx + ddy * ddy + ddz * ddz;
                int jg = jb + jj;
                if (r2 < CUTOFF2 && jg > i) {
                    bool skip = false;
                    for (int k = 0; k < ne; k++) skip = skip || (ex[k] == jg);
                    if (!skip) {
                        float r = sqrtf(r2);
                        e += (double)(qi * o.w * erfcf(ALPHA * r) / r);
                    }
                }
            }
        }
        e *= (double)COULOMB;

        // exactly one j-tile per i-superblock is the "anchor" (jb == ib):
        // fold in self-energy + exclusion corrections there.
        if (jb == ib) {
            const float inv_sqrt_pi = 0.5641895835477563f;
            e += (double)(-COULOMB * ALPHA * inv_sqrt_pi * qi * qi);
            for (int k = 0; k < E; k++) {
                int j = excl[i * E + k];
                if (j < 0) continue;
                float4 o = pxq[j];
                float dx = xi - o.x, dy = yi - o.y, dz = zi - o.z;
                if (B.diag) {
                    dx -= rintf(dx * B.inv[0]) * box[0];
                    dy -= rintf(dy * B.inv[4]) * box[4];
                    dz -= rintf(dz * B.inv[8]) * box[8];
                } else {
                    float s0 = dx * B.inv[0] + dy * B.inv[3] + dz * B.inv[6];
                    float s1 = dx * B.inv[1] + dy * B.inv[4] + dz * B.inv[7];
                    float s2 = dx * B.inv[2] + dy * B.inv[5] + dz * B.inv[8];
                    s0 -= rintf(s0);
                    s1 -= rintf(s1);
                    s2 -= rintf(s2);
                    dx = s0 * box[0] + s1 * box[3] + s2 * box[6];
                    dy = s0 * box[1] + s1 * box[4] + s2 * box[7];
                    dz = s0 * box[2] + s1 * box[5] + s2 * box[8];
                }
                float r2 = dx * dx + dy * dy + dz * dz;
                if (r2 > 0.0f) {
                    float r = sqrtf(r2);
                    e += (double)(-0.5f * COULOMB * qi * o.w * erff(ALPHA * r) / r);
                }
            }
        }
    }
    // wave shuffle reduce, then 4 wave leaders through LDS
#pragma unroll
    for (int off = 32; off > 0; off >>= 1) e += __shfl_down(e, off, 64);
    if ((tid & 63) == 0) wsum[tid >> 6] = e;
    __syncthreads();
    if (tid == 0)
        partD[blockIdx.y * gridDim.x + blockIdx.x] = wsum[0] + wsum[1] + wsum[2] + wsum[3];
}

// ---------------------------------------------------------------- 3D DFT, 64-pt lines
// ILP-8 twiddle scheme: 8 rotation chains with bases e1^g and step e8 = e1^8;
// 8 accumulator pairs. Breaks the 64-step serial chains of round 2.
struct Tw8 {
    float wc[8], ws[8], c8, s8, c1, s1;
};
__device__ __forceinline__ Tw8 make_tw8(int m) {
    Tw8 T;
    float s1, c1;
    sincosf(-2.0f * PI_F * (float)m / (float)KG, &s1, &c1);
    T.c1 = c1;
    T.s1 = s1;
    float c2 = c1 * c1 - s1 * s1, s2 = 2.0f * c1 * s1;
    float c4 = c2 * c2 - s2 * s2, s4 = 2.0f * c2 * s2;
    T.c8 = c4 * c4 - s4 * s4;
    T.s8 = 2.0f * c4 * s4;
    T.wc[0] = 1.0f;
    T.ws[0] = 0.0f;
    T.wc[1] = c1;
    T.ws[1] = s1;
    T.wc[2] = c2;
    T.ws[2] = s2;
    T.wc[3] = c2 * c1 - s2 * s1;
    T.ws[3] = c2 * s1 + s2 * c1;
    T.wc[4] = c4;
    T.ws[4] = s4;
    T.wc[5] = c4 * c1 - s4 * s1;
    T.ws[5] = c4 * s1 + s4 * c1;
    T.wc[6] = c4 * c2 - s4 * s2;
    T.ws[6] = c4 * s2 + s4 * c2;
    T.wc[7] = c4 * T.wc[3] - s4 * T.ws[3];
    T.ws[7] = c4 * T.ws[3] + s4 * T.wc[3];
    return T;
}

// pass 1: real grid[ix][iy][iz] -> bufA[ix][mz][iy].  4 lines / 256-thread block.
__global__ __launch_bounds__(256) void dft_z(const float* __restrict__ grid,
                                             float2* __restrict__ bufA) {
    __shared__ float g[4][KG];
    int tid = threadIdx.x, wv = tid >> 6, ln = tid & 63;
    int line = blockIdx.x * 4 + wv;  // ix*KG + iy
    g[wv][ln] = grid[line * KG + ln];
    __syncthreads();
    Tw8 T = make_tw8(ln);
    float rr[8] = {0}, ii[8] = {0};
#pragma unroll
    for (int s = 0; s < 8; s++) {
#pragma unroll
        for (int gg = 0; gg < 8; gg++) {
            float gv = g[wv][s * 8 + gg];
            rr[gg] = fmaf(gv, T.wc[gg], rr[gg]);
            ii[gg] = fmaf(gv, T.ws[gg], ii[gg]);
            float nc = T.wc[gg] * T.c8 - T.ws[gg] * T.s8;
            T.ws[gg] = T.wc[gg] * T.s8 + T.ws[gg] * T.c8;
            T.wc[gg] = nc;
        }
    }
    float re = ((rr[0] + rr[1]) + (rr[2] + rr[3])) + ((rr[4] + rr[5]) + (rr[6] + rr[7]));
    float im = ((ii[0] + ii[1]) + (ii[2] + ii[3])) + ((ii[4] + ii[5]) + (ii[6] + ii[7]));
    int ix = line >> 6, iy = line & 63;
    bufA[(ix * KG + ln) * KG + iy] = make_float2(re, im);
}

// pass 2: bufA[ix][mz][iy] -> bufB[my][mz][ix]
__global__ __launch_bounds__(256) void dft_y(const float2* __restrict__ bufA,
                                             float2* __restrict__ bufB) {
    __shared__ float2 c[4][KG];
    int tid = threadIdx.x, wv = tid >> 6, ln = tid & 63;
    int idx = blockIdx.x * 4 + wv;  // ix*KG + mz
    int ix = idx >> 6, mz = idx & 63;
    c[wv][ln] = bufA[(ix * KG + mz) * KG + ln];
    __syncthreads();
    Tw8 T = make_tw8(ln);
    float rr[8] = {0}, ii[8] = {0};
#pragma unroll
    for (int s = 0; s < 8; s++) {
#pragma unroll
        for (int gg = 0; gg < 8; gg++) {
            float2 a = c[wv][s * 8 + gg];
            rr[gg] += a.x * T.wc[gg] - a.y * T.ws[gg];
            ii[gg] += a.x * T.ws[gg] + a.y * T.wc[gg];
            float nc = T.wc[gg] * T.c8 - T.ws[gg] * T.s8;
            T.ws[gg] = T.wc[gg] * T.s8 + T.ws[gg] * T.c8;
            T.wc[gg] = nc;
        }
    }
    float re = ((rr[0] + rr[1]) + (rr[2] + rr[3])) + ((rr[4] + rr[5]) + (rr[6] + rr[7]));
    float im = ((ii[0] + ii[1]) + (ii[2] + ii[3])) + ((ii[4] + ii[5]) + (ii[6] + ii[7]));
    bufB[(ln * KG + mz) * KG + ix] = make_float2(re, im);
}

__device__ __forceinline__ float bmod4(float c1, float s1) {
    float c2 = 2.0f * c1 * c1 - 1.0f;
    float s2 = 2.0f * s1 * c1;
    float br = (1.0f + 4.0f * c1 + c2) * (1.0f / 6.0f);
    float bi = (4.0f * s1 + s2) * (1.0f / 6.0f);
    float d2 = br * br + bi * bi;
    return 1.0f / fmaxf(d2, 1e-7f);
}

// pass 3 + influence reduction: bufB[my][mz][ix], lane = mx. Per-wave partial -> partR.
__global__ __launch_bounds__(256) void dft_x_reduce(const float2* __restrict__ bufB,
                                                    const float* __restrict__ box,
                                                    double* __restrict__ partR) {
    __shared__ float2 c[4][KG];
    int tid = threadIdx.x, wv = tid >> 6, ln = tid & 63;
    int idx = blockIdx.x * 4 + wv;  // my*KG + mz
    int my = idx >> 6, mz = idx & 63;
    c[wv][ln] = bufB[(my * KG + mz) * KG + ln];
    __syncthreads();
    Tw8 T = make_tw8(ln);
    float rr[8] = {0}, ii[8] = {0};
#pragma unroll
    for (int s = 0; s < 8; s++) {
#pragma unroll
        for (int gg = 0; gg < 8; gg++) {
            float2 a = c[wv][s * 8 + gg];
            rr[gg] += a.x * T.wc[gg] - a.y * T.ws[gg];
            ii[gg] += a.x * T.ws[gg] + a.y * T.wc[gg];
            float nc = T.wc[gg] * T.c8 - T.ws[gg] * T.s8;
            T.ws[gg] = T.wc[gg] * T.s8 + T.ws[gg] * T.c8;
            T.wc[gg] = nc;
        }
    }
    float re = ((rr[0] + rr[1]) + (rr[2] + rr[3])) + ((rr[4] + rr[5]) + (rr[6] + rr[7]));
    float im = ((ii[0] + ii[1]) + (ii[2] + ii[3])) + ((ii[4] + ii[5]) + (ii[6] + ii[7]));
    float sq = re * re + im * im;

    BoxInfo B = load_box(box);
    int mx = ln;
    int msx = (mx < KG / 2) ? mx : mx - KG;
    int msy = (my < KG / 2) ? my : my - KG;
    int msz = (mz < KG / 2) ? mz : mz - KG;
    float fmx = (float)msx, fmy = (float)msy, fmz = (float)msz;
    float kx = fmx * B.inv[0] + fmy * B.inv[1] + fmz * B.inv[2];
    float ky = fmx * B.inv[3] + fmy * B.inv[4] + fmz * B.inv[5];
    float kz = fmx * B.inv[6] + fmy * B.inv[7] + fmz * B.inv[8];
    float msq = kx * kx + ky * ky + kz * kz;
    const float cexp = (PI_F * PI_F) / (ALPHA * ALPHA);
    float infl = (msq > 0.0f) ? expf(-cexp * msq) / msq : 0.0f;

    float bx_ = bmod4(T.c1, T.s1);  // |b|^2 is even in the sin sign
    float sy, cy, sz, cz;
    sincosf(2.0f * PI_F * (float)my / (float)KG, &sy, &cy);
    sincosf(2.0f * PI_F * (float)mz / (float)KG, &sz, &cz);
    float by_ = bmod4(cy, sy);
    float bz_ = bmod4(cz, sz);

    float pref = COULOMB / (2.0f * PI_F * B.vol);
    double term = (double)(pref * infl * bx_ * by_ * bz_ * sq);

#pragma unroll
    for (int off = 32; off > 0; off >>= 1) term += __shfl_down(term, off, 64);
    if (ln == 0) partR[blockIdx.x * 4 + wv] = term;
}

// ---------------------------------------------------------------- final reduce
__global__ __launch_bounds__(1024) void final_reduce(const double* __restrict__ parts, int n,
                                                     float* __restrict__ out) {
    __shared__ double wsum[16];
    int tid = threadIdx.x;
    double s = 0.0;
    for (int k = tid; k < n; k += 1024) s += parts[k];
#pragma unroll
    for (int off = 32; off > 0; off >>= 1) s += __shfl_down(s, off, 64);
    if ((tid & 63) == 0) wsum[tid >> 6] = s;
    __syncthreads();
    if (tid == 0) {
        double t = 0.0;
#pragma unroll
        for (int w = 0; w < 16; w++) t += wsum[w];
        out[0] = (float)t;
    }
}

// ---------------------------------------------------------------- launch

extern "C" void kernel_launch(void* const* d_in, const int* in_sizes, int n_in,
                              void* d_out, int out_size, void* d_ws, size_t ws_size,
                              hipStream_t stream) {
    const float* pos = (const float*)d_in[0];
    const float* chg = (const float*)d_in[1];
    const float* box = (const float*)d_in[2];
    const int* excl = (const int*)d_in[3];
    int N = in_sizes[0] / 3;
    int E = in_sizes[3] / N;

    char* ws = (char*)d_ws;
    // layout:
    //   [4096, 12288)        partD: 1024 doubles (direct partials)
    //   [12288, 45056)       partR: 4096 doubles (recip partials)
    //   [65536, 65536+1MB)   real grid
    //   then bufA (2MB), bufB (2MB); pxq aliases bufB (direct reads it before dft_y writes)
    double* partD = (double*)(ws + 4096);
    double* partR = (double*)(ws + 12288);
    double* parts = (double*)(ws + 4096);  // contiguous 5120 doubles
    float* grid = (float*)(ws + 65536);
    float2* bufA = (float2*)(ws + 65536 + 4 * (size_t)KG3);
    float2* bufB = (float2*)(ws + 65536 + 12 * (size_t)KG3);
    float4* pxq = (float4*)bufB;

    // zero partials + grid (ws is poisoned 0xAA before every timed call)
    hipMemsetAsync(ws, 0, 65536 + 4 * (size_t)KG3, stream);

    spread_kernel<<<(N + 255) / 256, 256, 0, stream>>>(pos, chg, box, grid, pxq, N);

    int nib = (N + DIB - 1) / DIB;   // 16
    int njt = (N + DJT - 1) / DJT;   // 64
    dim3 dg(nib, njt);
    direct_kernel<<<dg, 256, 0, stream>>>(pxq, box, excl, N, E, partD);

    dft_z<<<KG * KG / 4, 256, 0, stream>>>(grid, bufA);
    dft_y<<<KG * KG / 4, 256, 0, stream>>>(bufA, bufB);
    dft_x_reduce<<<KG * KG / 4, 256, 0, stream>>>(bufB, box, partR);

    int nparts = nib * njt + KG * KG;  // 1024 + 4096
    final_reduce<<<1, 1024, 0, stream>>>(parts, nparts, (float*)d_out);
}

// Round 4
// 131.252 us; speedup vs baseline: 2.0455x; 1.1968x over previous
//
#include <hip/hip_runtime.h>
#include <math.h>
#include <stdint.h>

#define KG 64
#define KG3 (KG * KG * KG)
#define MZK 33  // Hermitian: keep mz in [0,32]
#define ALPHA 0.34f
#define COULOMB 138.935456f
#define CUTOFF2 81.0f
#define PI_F 3.14159265358979323846f

// ---------------------------------------------------------------- box helpers
struct BoxInfo {
    float inv[9];
    float vol;
    bool diag;
};
__device__ __forceinline__ BoxInfo load_box(const float* __restrict__ box) {
    BoxInfo b;
    float b0 = box[0], b1 = box[1], b2 = box[2];
    float b3 = box[3], b4 = box[4], b5 = box[5];
    float b6 = box[6], b7 = box[7], b8 = box[8];
    float det = b0 * (b4 * b8 - b5 * b7) - b1 * (b3 * b8 - b5 * b6) + b2 * (b3 * b7 - b4 * b6);
    float id = 1.0f / det;
    b.inv[0] = (b4 * b8 - b5 * b7) * id;
    b.inv[1] = (b2 * b7 - b1 * b8) * id;
    b.inv[2] = (b1 * b5 - b2 * b4) * id;
    b.inv[3] = (b5 * b6 - b3 * b8) * id;
    b.inv[4] = (b0 * b8 - b2 * b6) * id;
    b.inv[5] = (b2 * b3 - b0 * b5) * id;
    b.inv[6] = (b3 * b7 - b4 * b6) * id;
    b.inv[7] = (b1 * b6 - b0 * b7) * id;
    b.inv[8] = (b0 * b4 - b1 * b3) * id;
    b.vol = fabsf(det);
    b.diag = (b1 == 0.0f) && (b2 == 0.0f) && (b3 == 0.0f) && (b5 == 0.0f) && (b6 == 0.0f) &&
             (b7 == 0.0f);
    return b;
}

// fast erfc, Abramowitz-Stegun 7.1.26, |abs err| < 1.5e-7 for x >= 0
__device__ __forceinline__ float erfc_fast(float x) {
    float t = __builtin_amdgcn_rcpf(fmaf(0.3275911f, x, 1.0f));
    float p = fmaf(t, 1.061405429f, -1.453152027f);
    p = fmaf(t, p, 1.421413741f);
    p = fmaf(t, p, -0.284496736f);
    p = fmaf(t, p, 0.254829592f);
    return t * p * __expf(-x * x);
}

// ---------------------------------------------------------------- spreading
__device__ __forceinline__ void bspline4(float t, float* w) {
    float w0 = 1.0f - t, w1 = t;
    float a2 = 0.5f * t * w1;
    float a1 = 0.5f * ((t + 1.0f) * w0 + (2.0f - t) * w1);
    float a0 = 0.5f * (1.0f - t) * w0;
    const float d = 1.0f / 3.0f;
    w[3] = d * t * a2;
    w[2] = d * ((t + 1.0f) * a1 + (3.0f - t) * a2);
    w[1] = d * ((t + 2.0f) * a0 + (2.0f - t) * a1);
    w[0] = d * (1.0f - t) * a0;
}

// 4 threads per atom (one per jx-slab) -> 4x the waves of round 3.
__global__ __launch_bounds__(256) void spread_kernel(const float* __restrict__ pos,
                                                     const float* __restrict__ chg,
                                                     const float* __restrict__ box,
                                                     float* __restrict__ grid,
                                                     float4* __restrict__ pxq, int N) {
    int t4 = blockIdx.x * blockDim.x + threadIdx.x;
    int i = t4 >> 2, jx = t4 & 3;
    if (i >= N) return;
    BoxInfo B = load_box(box);
    float p0 = pos[3 * i], p1 = pos[3 * i + 1], p2 = pos[3 * i + 2];
    float q = chg[i];
    if (jx == 0) pxq[i] = make_float4(p0, p1, p2, q);
    float w[3][4];
    int idx[3][4];
#pragma unroll
    for (int a = 0; a < 3; a++) {
        float f = p0 * B.inv[0 * 3 + a] + p1 * B.inv[1 * 3 + a] + p2 * B.inv[2 * 3 + a];
        f -= floorf(f);
        float u = f * (float)KG;
        float fu = floorf(u);
        int base = (int)fu;
        float tt = u - fu;
        bspline4(tt, w[a]);
#pragma unroll
        for (int j = 0; j < 4; j++) idx[a][j] = (base - 3 + j + 2 * KG) & (KG - 1);
    }
    float qx = q * w[0][jx];
    int bx = idx[0][jx] * KG;
#pragma unroll
    for (int jy = 0; jy < 4; jy++) {
        float qxy = qx * w[1][jy];
        int bxy = (bx + idx[1][jy]) * KG;
#pragma unroll
        for (int jz = 0; jz < 4; jz++) {
            atomicAdd(&grid[bxy + idx[2][jz]], qxy * w[2][jz]);
        }
    }
}

// ---------------------------------------------------------------- direct space
// Block = 256 i-atoms vs one 32-atom j-tile (more waves than 64-tiles).
// Branchless inner loop with fast erfc; partials -> partD (pre-zeroed).
#define DIB 256
#define DJT 32
__global__ __launch_bounds__(256) void direct_kernel(const float4* __restrict__ pxq,
                                                     const float* __restrict__ box,
                                                     const int* __restrict__ excl, int N, int E,
                                                     double* __restrict__ partD) {
    int ib = blockIdx.x * DIB, jb = blockIdx.y * DJT;
    if (jb + DJT <= ib) return;  // fully lower-triangular

    __shared__ float4 sj[DJT];
    __shared__ double wsum[4];
    int tid = threadIdx.x;
    if (tid < DJT) {
        int jg0 = jb + tid;
        sj[tid] = (jg0 < N) ? pxq[jg0] : make_float4(0.0f, 0.0f, 0.0f, 0.0f);
    }
    __syncthreads();

    BoxInfo B = load_box(box);
    double e = 0.0;
    int i = ib + tid;
    if (i < N) {
        float4 me = pxq[i];
        float xi = me.x, yi = me.y, zi = me.z, qi = me.w;
        int ex0 = -1, ex1 = -1;
        int ne = (E < 8) ? E : 8;
        int ex[8];
        for (int k = 0; k < ne; k++) ex[k] = excl[i * E + k];

        float fsum = 0.0f;
        if (B.diag) {
            float Lx = box[0], Ly = box[4], Lz = box[8];
            float ivx = B.inv[0], ivy = B.inv[4], ivz = B.inv[8];
#pragma unroll 8
            for (int jj = 0; jj < DJT; jj++) {
                float4 o = sj[jj];
                int jg = jb + jj;
                float dx = xi - o.x, dy = yi - o.y, dz = zi - o.z;
                dx -= rintf(dx * ivx) * Lx;
                dy -= rintf(dy * ivy) * Ly;
                dz -= rintf(dz * ivz) * Lz;
                float r2 = fmaf(dx, dx, fmaf(dy, dy, dz * dz));
                bool valid = (r2 < CUTOFF2) & (jg > i) & (jg < N);
                for (int k = 0; k < ne; k++) valid = valid & (ex[k] != jg);
                float r2m = valid ? r2 : 1.0f;
                float rinv = __builtin_amdgcn_rsqf(r2m);
                float r = r2m * rinv;
                float g = erfc_fast(ALPHA * r) * rinv;
                float qqm = valid ? qi * o.w : 0.0f;
                fsum = fmaf(qqm, g, fsum);
            }
        } else {
#pragma unroll 4
            for (int jj = 0; jj < DJT; jj++) {
                float4 o = sj[jj];
                int jg = jb + jj;
                float dx = xi - o.x, dy = yi - o.y, dz = zi - o.z;
                float s0 = dx * B.inv[0] + dy * B.inv[3] + dz * B.inv[6];
                float s1 = dx * B.inv[1] + dy * B.inv[4] + dz * B.inv[7];
                float s2 = dx * B.inv[2] + dy * B.inv[5] + dz * B.inv[8];
                s0 -= rintf(s0);
                s1 -= rintf(s1);
                s2 -= rintf(s2);
                float ddx = s0 * box[0] + s1 * box[3] + s2 * box[6];
                float ddy = s0 * box[1] + s1 * box[4] + s2 * box[7];
                float ddz = s0 * box[2] + s1 * box[5] + s2 * box[8];
                float r2 = fmaf(ddx, ddx, fmaf(ddy, ddy, ddz * ddz));
                bool valid = (r2 < CUTOFF2) & (jg > i) & (jg < N);
                for (int k = 0; k < ne; k++) valid = valid & (ex[k] != jg);
                float r2m = valid ? r2 : 1.0f;
                float rinv = __builtin_amdgcn_rsqf(r2m);
                float r = r2m * rinv;
                float g = erfc_fast(ALPHA * r) * rinv;
                float qqm = valid ? qi * o.w : 0.0f;
                fsum = fmaf(qqm, g, fsum);
            }
        }
        e = (double)(COULOMB * fsum);

        // one anchor j-tile per i-superblock: self-energy + exclusion corrections
        if (jb == ib) {
            const float inv_sqrt_pi = 0.5641895835477563f;
            float corr = -ALPHA * inv_sqrt_pi * qi * qi;
            for (int k = 0; k < ne; k++) {
                int j = ex[k];
                if (j < 0) continue;
                float4 o = pxq[j];
                float dx = xi - o.x, dy = yi - o.y, dz = zi - o.z;
                if (B.diag) {
                    dx -= rintf(dx * B.inv[0]) * box[0];
                    dy -= rintf(dy * B.inv[4]) * box[4];
                    dz -= rintf(dz * B.inv[8]) * box[8];
                } else {
                    float s0 = dx * B.inv[0] + dy * B.inv[3] + dz * B.inv[6];
                    float s1 = dx * B.inv[1] + dy * B.inv[4] + dz * B.inv[7];
                    float s2 = dx * B.inv[2] + dy * B.inv[5] + dz * B.inv[8];
                    s0 -= rintf(s0);
                    s1 -= rintf(s1);
                    s2 -= rintf(s2);
                    dx = s0 * box[0] + s1 * box[3] + s2 * box[6];
                    dy = s0 * box[1] + s1 * box[4] + s2 * box[7];
                    dz = s0 * box[2] + s1 * box[5] + s2 * box[8];
                }
                float r2 = dx * dx + dy * dy + dz * dz;
                if (r2 > 0.0f) {
                    float rinv = __builtin_amdgcn_rsqf(r2);
                    float r = r2 * rinv;
                    float erfv = 1.0f - erfc_fast(ALPHA * r);
                    corr += -0.5f * qi * o.w * erfv * rinv;
                }
            }
            e += (double)(COULOMB * corr);
        }
    }
#pragma unroll
    for (int off = 32; off > 0; off >>= 1) e += __shfl_down(e, off, 64);
    if ((tid & 63) == 0) wsum[tid >> 6] = e;
    __syncthreads();
    if (tid == 0)
        partD[blockIdx.y * gridDim.x + blockIdx.x] = wsum[0] + wsum[1] + wsum[2] + wsum[3];
}

// ---------------------------------------------------------------- 3D DFT, 64-pt lines
// ILP-8 twiddle chains; Hermitian symmetry halves passes 2-3 (mz in [0,32]).
struct Tw8 {
    float wc[8], ws[8], c8, s8, c1, s1;
};
__device__ __forceinline__ Tw8 make_tw8(int m) {
    Tw8 T;
    float s1, c1;
    __sincosf(-2.0f * PI_F * (float)m / (float)KG, &s1, &c1);
    T.c1 = c1;
    T.s1 = s1;
    float c2 = c1 * c1 - s1 * s1, s2 = 2.0f * c1 * s1;
    float c4 = c2 * c2 - s2 * s2, s4 = 2.0f * c2 * s2;
    T.c8 = c4 * c4 - s4 * s4;
    T.s8 = 2.0f * c4 * s4;
    T.wc[0] = 1.0f;
    T.ws[0] = 0.0f;
    T.wc[1] = c1;
    T.ws[1] = s1;
    T.wc[2] = c2;
    T.ws[2] = s2;
    T.wc[3] = c2 * c1 - s2 * s1;
    T.ws[3] = c2 * s1 + s2 * c1;
    T.wc[4] = c4;
    T.ws[4] = s4;
    T.wc[5] = c4 * c1 - s4 * s1;
    T.ws[5] = c4 * s1 + s4 * c1;
    T.wc[6] = c4 * c2 - s4 * s2;
    T.ws[6] = c4 * s2 + s4 * c2;
    T.wc[7] = c4 * T.wc[3] - s4 * T.ws[3];
    T.ws[7] = c4 * T.ws[3] + s4 * T.wc[3];
    return T;
}

// pass 1: real grid[ix][iy][iz] -> bufA[ix][mz][iy], mz<=32 only.
__global__ __launch_bounds__(256) void dft_z(const float* __restrict__ grid,
                                             float2* __restrict__ bufA) {
    __shared__ float g[4][KG];
    int tid = threadIdx.x, wv = tid >> 6, ln = tid & 63;
    int line = blockIdx.x * 4 + wv;  // ix*KG + iy
    g[wv][ln] = grid[line * KG + ln];
    __syncthreads();
    Tw8 T = make_tw8(ln);
    float rr[8] = {0}, ii[8] = {0};
#pragma unroll
    for (int s = 0; s < 8; s++) {
#pragma unroll
        for (int gg = 0; gg < 8; gg++) {
            float gv = g[wv][s * 8 + gg];
            rr[gg] = fmaf(gv, T.wc[gg], rr[gg]);
            ii[gg] = fmaf(gv, T.ws[gg], ii[gg]);
            float nc = T.wc[gg] * T.c8 - T.ws[gg] * T.s8;
            T.ws[gg] = T.wc[gg] * T.s8 + T.ws[gg] * T.c8;
            T.wc[gg] = nc;
        }
    }
    if (ln < MZK) {
        float re = ((rr[0] + rr[1]) + (rr[2] + rr[3])) + ((rr[4] + rr[5]) + (rr[6] + rr[7]));
        float im = ((ii[0] + ii[1]) + (ii[2] + ii[3])) + ((ii[4] + ii[5]) + (ii[6] + ii[7]));
        int ix = line >> 6, iy = line & 63;
        bufA[(ix * KG + ln) * KG + iy] = make_float2(re, im);
    }
}

// pass 2: bufA[ix][mz][iy] -> bufB[my][mz][ix], lines = (ix, mz in [0,33))
__global__ __launch_bounds__(256) void dft_y(const float2* __restrict__ bufA,
                                             float2* __restrict__ bufB) {
    __shared__ float2 c[4][KG];
    int tid = threadIdx.x, wv = tid >> 6, ln = tid & 63;
    int idx = blockIdx.x * 4 + wv;
    if (idx >= KG * MZK) return;
    int ix = idx / MZK, mz = idx - ix * MZK;
    c[wv][ln] = bufA[(ix * KG + mz) * KG + ln];
    __syncthreads();
    Tw8 T = make_tw8(ln);
    float rr[8] = {0}, ii[8] = {0};
#pragma unroll
    for (int s = 0; s < 8; s++) {
#pragma unroll
        for (int gg = 0; gg < 8; gg++) {
            float2 a = c[wv][s * 8 + gg];
            rr[gg] += a.x * T.wc[gg] - a.y * T.ws[gg];
            ii[gg] += a.x * T.ws[gg] + a.y * T.wc[gg];
            float nc = T.wc[gg] * T.c8 - T.ws[gg] * T.s8;
            T.ws[gg] = T.wc[gg] * T.s8 + T.ws[gg] * T.c8;
            T.wc[gg] = nc;
        }
    }
    float re = ((rr[0] + rr[1]) + (rr[2] + rr[3])) + ((rr[4] + rr[5]) + (rr[6] + rr[7]));
    float im = ((ii[0] + ii[1]) + (ii[2] + ii[3])) + ((ii[4] + ii[5]) + (ii[6] + ii[7]));
    bufB[(ln * MZK + mz) * KG + ix] = make_float2(re, im);
}

__device__ __forceinline__ float bmod4(float c1, float s1) {
    float c2 = 2.0f * c1 * c1 - 1.0f;
    float s2 = 2.0f * s1 * c1;
    float br = (1.0f + 4.0f * c1 + c2) * (1.0f / 6.0f);
    float bi = (4.0f * s1 + s2) * (1.0f / 6.0f);
    float d2 = br * br + bi * bi;
    return 1.0f / fmaxf(d2, 1e-7f);
}

// pass 3 + influence: bufB[my][mz][ix], lines = (my, mz in [0,33)), lane = mx.
// Hermitian weight: 2 for mz in [1,31], 1 for mz = 0, 32.
__global__ __launch_bounds__(256) void dft_x_reduce(const float2* __restrict__ bufB,
                                                    const float* __restrict__ box,
                                                    double* __restrict__ partR) {
    __shared__ float2 c[4][KG];
    int tid = threadIdx.x, wv = tid >> 6, ln = tid & 63;
    int idx = blockIdx.x * 4 + wv;
    if (idx >= KG * MZK) return;
    int my = idx / MZK, mz = idx - my * MZK;
    c[wv][ln] = bufB[(my * MZK + mz) * KG + ln];
    __syncthreads();
    Tw8 T = make_tw8(ln);
    float rr[8] = {0}, ii[8] = {0};
#pragma unroll
    for (int s = 0; s < 8; s++) {
#pragma unroll
        for (int gg = 0; gg < 8; gg++) {
            float2 a = c[wv][s * 8 + gg];
            rr[gg] += a.x * T.wc[gg] - a.y * T.ws[gg];
            ii[gg] += a.x * T.ws[gg] + a.y * T.wc[gg];
            float nc = T.wc[gg] * T.c8 - T.ws[gg] * T.s8;
            T.ws[gg] = T.wc[gg] * T.s8 + T.ws[gg] * T.c8;
            T.wc[gg] = nc;
        }
    }
    float re = ((rr[0] + rr[1]) + (rr[2] + rr[3])) + ((rr[4] + rr[5]) + (rr[6] + rr[7]));
    float im = ((ii[0] + ii[1]) + (ii[2] + ii[3])) + ((ii[4] + ii[5]) + (ii[6] + ii[7]));
    float sq = re * re + im * im;

    BoxInfo B = load_box(box);
    int mx = ln;
    int msx = (mx < KG / 2) ? mx : mx - KG;
    int msy = (my < KG / 2) ? my : my - KG;
    int msz = (mz < KG / 2) ? mz : mz - KG;
    float fmx = (float)msx, fmy = (float)msy, fmz = (float)msz;
    float kx = fmx * B.inv[0] + fmy * B.inv[1] + fmz * B.inv[2];
    float ky = fmx * B.inv[3] + fmy * B.inv[4] + fmz * B.inv[5];
    float kz = fmx * B.inv[6] + fmy * B.inv[7] + fmz * B.inv[8];
    float msq = kx * kx + ky * ky + kz * kz;
    const float cexp = (PI_F * PI_F) / (ALPHA * ALPHA);
    float infl = (msq > 0.0f) ? __expf(-cexp * msq) / msq : 0.0f;

    float bx_ = bmod4(T.c1, T.s1);
    float sy, cy, sz, cz;
    __sincosf(2.0f * PI_F * (float)my / (float)KG, &sy, &cy);
    __sincosf(2.0f * PI_F * (float)mz / (float)KG, &sz, &cz);
    float by_ = bmod4(cy, sy);
    float bz_ = bmod4(cz, sz);

    float wgt = (mz == 0 || mz == 32) ? 1.0f : 2.0f;
    float pref = COULOMB / (2.0f * PI_F * B.vol);
    double term = (double)(wgt * pref * infl * bx_ * by_ * bz_ * sq);

#pragma unroll
    for (int off = 32; off > 0; off >>= 1) term += __shfl_down(term, off, 64);
    if (ln == 0) partR[idx] = term;
}

// ---------------------------------------------------------------- final reduce
__global__ __launch_bounds__(1024) void final_reduce(const double* __restrict__ parts, int n,
                                                     float* __restrict__ out) {
    __shared__ double wsum[16];
    int tid = threadIdx.x;
    double s = 0.0;
    for (int k = tid; k < n; k += 1024) s += parts[k];
#pragma unroll
    for (int off = 32; off > 0; off >>= 1) s += __shfl_down(s, off, 64);
    if ((tid & 63) == 0) wsum[tid >> 6] = s;
    __syncthreads();
    if (tid == 0) {
        double t = 0.0;
#pragma unroll
        for (int w = 0; w < 16; w++) t += wsum[w];
        out[0] = (float)t;
    }
}

// ---------------------------------------------------------------- launch

extern "C" void kernel_launch(void* const* d_in, const int* in_sizes, int n_in,
                              void* d_out, int out_size, void* d_ws, size_t ws_size,
                              hipStream_t stream) {
    const float* pos = (const float*)d_in[0];
    const float* chg = (const float*)d_in[1];
    const float* box = (const float*)d_in[2];
    const int* excl = (const int*)d_in[3];
    int N = in_sizes[0] / 3;
    int E = in_sizes[3] / N;

    char* ws = (char*)d_ws;
    // [4096, 20480)  partD: 2048 doubles   [20480, 37376) partR: 2112 doubles
    // [65536, +1MB)  real grid; then bufA (2MB region), bufB (2MB region).
    // pxq aliases bufB start: direct_kernel reads it before dft_y writes bufB.
    double* partD = (double*)(ws + 4096);
    double* partR = (double*)(ws + 20480);
    double* parts = (double*)(ws + 4096);
    float* grid = (float*)(ws + 65536);
    float2* bufA = (float2*)(ws + 65536 + 4 * (size_t)KG3);
    float2* bufB = (float2*)(ws + 65536 + 12 * (size_t)KG3);
    float4* pxq = (float4*)bufB;

    hipMemsetAsync(ws, 0, 65536 + 4 * (size_t)KG3, stream);  // partials + grid

    spread_kernel<<<(4 * N + 255) / 256, 256, 0, stream>>>(pos, chg, box, grid, pxq, N);

    int nib = (N + DIB - 1) / DIB;  // 16
    int njt = (N + DJT - 1) / DJT;  // 128
    dim3 dg(nib, njt);
    direct_kernel<<<dg, 256, 0, stream>>>(pxq, box, excl, N, E, partD);

    dft_z<<<KG * KG / 4, 256, 0, stream>>>(grid, bufA);
    int nlines = KG * MZK;  // 2112
    dft_y<<<(nlines + 3) / 4, 256, 0, stream>>>(bufA, bufB);
    dft_x_reduce<<<(nlines + 3) / 4, 256, 0, stream>>>(bufB, box, partR);

    int nparts = nib * njt + nlines;  // 2048 + 2112
    final_reduce<<<1, 1024, 0, stream>>>(parts, nparts, (float*)d_out);
}